// Round 1
// baseline (350.177 us; speedup 1.0000x reference)
//
#include <hip/hip_runtime.h>
#include <math.h>

#define NTHREADS 256
#define KSEL 100
#define SCORE_TH 0.1f
#define NMS_TH 0.1f
#define BELONG_TH 0.6f

// Pack (value, index) so that u64 max == (max value, min index on ties).
__device__ __forceinline__ unsigned long long make_key(float f, unsigned gidx) {
    unsigned u = __float_as_uint(f);
    u = (u & 0x80000000u) ? ~u : (u | 0x80000000u);
    return (((unsigned long long)u) << 32) | (unsigned long long)(0xFFFFFFFFu - gidx);
}
__device__ __forceinline__ float key_val(unsigned long long k) {
    unsigned u = (unsigned)(k >> 32);
    u = (u & 0x80000000u) ? (u ^ 0x80000000u) : ~u;
    return __uint_as_float(u);
}
__device__ __forceinline__ unsigned key_idx(unsigned long long k) {
    return 0xFFFFFFFFu - (unsigned)(k & 0xFFFFFFFFu);
}

struct SharedMem {
    unsigned long long part[4];
    float prob[KSEL];
    int   sidx[KSEL];
    float box[KSEL][4];
    float data16[KSEL][16];
    float area[KSEL];
    float belong[KSEL];
    unsigned char keep[KSEL];
    unsigned char valid[KSEL];
    unsigned char nk[KSEL];
    int argm;
    int anyvk;
};

template <int NPT, bool IS_BEZIER, bool HAS_PARENT>
__device__ void filter_impl(SharedMem* sm,
                            const float* __restrict__ logits,
                            const float* __restrict__ raw,
                            const float* __restrict__ parent_raw,
                            const float* __restrict__ tsizes,
                            float* __restrict__ out_data,
                            float* __restrict__ out_scores,
                            float* __restrict__ out_keep,
                            int img, int N, int PN, int ef) {
    const int tid = threadIdx.x;
    const float* lg = logits + (size_t)img * N;

    // ---- load + sigmoid into registers (fully unrolled -> stays in VGPRs) ----
    float p[NPT];
#pragma unroll
    for (int j = 0; j < NPT; ++j) {
        float x = lg[j * NTHREADS + tid];
        p[j] = 1.0f / (1.0f + expf(-x));
    }
    unsigned long long best = make_key(p[0], (unsigned)tid);
#pragma unroll
    for (int j = 1; j < NPT; ++j) {
        unsigned long long kk = make_key(p[j], (unsigned)(j * NTHREADS + tid));
        if (kk > best) best = kk;
    }

    // ---- iterative top-100 selection ----
    for (int k = 0; k < KSEL; ++k) {
        unsigned long long m = best;
#pragma unroll
        for (int off = 32; off > 0; off >>= 1) {
            unsigned long long o = __shfl_down(m, off, 64);
            if (o > m) m = o;
        }
        if ((tid & 63) == 0) sm->part[tid >> 6] = m;
        __syncthreads();
        unsigned long long w = sm->part[0];
#pragma unroll
        for (int q = 1; q < 4; ++q)
            if (sm->part[q] > w) w = sm->part[q];
        if (tid == 0) {
            sm->prob[k] = key_val(w);
            sm->sidx[k] = (int)key_idx(w);
        }
        __syncthreads();  // part[] safe to overwrite next iter
        unsigned gidx = key_idx(w);
        if ((gidx & (NTHREADS - 1)) == (unsigned)tid) {
            int j = (int)(gidx >> 8);  // NTHREADS == 256
#pragma unroll
            for (int jj = 0; jj < NPT; ++jj)
                if (jj == j) p[jj] = -INFINITY;
            best = make_key(p[0], (unsigned)tid);
#pragma unroll
            for (int jj = 1; jj < NPT; ++jj) {
                unsigned long long kk = make_key(p[jj], (unsigned)(jj * NTHREADS + tid));
                if (kk > best) best = kk;
            }
        }
    }
    __syncthreads();

    const float Himg = tsizes[img * 2 + 0];
    const float Wimg = tsizes[img * 2 + 1];

    // ---- per-selected-box decode (threads 0..99) ----
    if (tid < KSEL) {
        const int k = tid;
        const int si = sm->sidx[k];
        const float val = sm->prob[k];
        const bool any = sm->prob[0] > SCORE_TH;  // sorted desc => any == keep[0]
        bool keep = any ? (val > SCORE_TH) : (k == 0);

        float bx1, by1, bx2, by2;
        if (IS_BEZIER) {
            const float* r = raw + ((size_t)img * N + si) * 16;
            float c[16];
#pragma unroll
            for (int mm = 0; mm < 8; ++mm) {
                c[2 * mm]     = r[2 * mm]     * Himg;  // tile((h,w),8): even -> h
                c[2 * mm + 1] = r[2 * mm + 1] * Wimg;  // odd -> w
            }
            float mn0 = INFINITY, mn1 = INFINITY, mx0 = -INFINITY, mx1 = -INFINITY;
            const float step = 1.0f / 9.0f;
#pragma unroll
            for (int s = 0; s < 10; ++s) {
                float t = (float)s * step;
                float ti = 1.0f - t;
                float b0 = ti * ti * ti;
                float b1 = 3.0f * t * ti * ti;
                float b2 = 3.0f * t * t * ti;
                float b3 = t * t * t;
#pragma unroll
                for (int cu = 0; cu < 2; ++cu) {
                    const float* cc = c + cu * 8;
                    float p0 = b0 * cc[0] + b1 * cc[2] + b2 * cc[4] + b3 * cc[6];
                    float p1 = b0 * cc[1] + b1 * cc[3] + b2 * cc[5] + b3 * cc[7];
                    mn0 = fminf(mn0, p0); mx0 = fmaxf(mx0, p0);
                    mn1 = fminf(mn1, p1); mx1 = fmaxf(mx1, p1);
                }
            }
            bx1 = mn0; by1 = mn1; bx2 = mx0; by2 = mx1;
#pragma unroll
            for (int mm = 0; mm < 16; ++mm) sm->data16[k][mm] = c[mm];
        } else {
            const float* r = raw + ((size_t)img * N + si) * 4;
            float cx = r[0], cy = r[1], w = r[2], h = r[3];
            bx1 = (cx - 0.5f * w) * Wimg;
            by1 = (cy - 0.5f * h) * Himg;
            bx2 = (cx + 0.5f * w) * Wimg;
            by2 = (cy + 0.5f * h) * Himg;
            if (!HAS_PARENT) {  // block level: clip to [0, (W,H)]
                bx1 = fminf(fmaxf(bx1, 0.0f), Wimg);
                by1 = fminf(fmaxf(by1, 0.0f), Himg);
                bx2 = fminf(fmaxf(bx2, 0.0f), Wimg);
                by2 = fminf(fmaxf(by2, 0.0f), Himg);
            }
        }
        sm->box[k][0] = bx1; sm->box[k][1] = by1;
        sm->box[k][2] = bx2; sm->box[k][3] = by2;
        sm->area[k] = (bx2 - bx1) * (by2 - by1);
        sm->keep[k] = keep ? 1 : 0;

        if (HAS_PARENT) {
            int pi = si / ef;
            const float* pr = parent_raw + ((size_t)img * PN + pi) * 4;
            float pcx = pr[0], pcy = pr[1], pw = pr[2], ph = pr[3];
            float px1 = (pcx - 0.5f * pw) * Wimg;
            float py1 = (pcy - 0.5f * ph) * Himg;
            float px2 = (pcx + 0.5f * pw) * Wimg;
            float py2 = (pcy + 0.5f * ph) * Himg;
            float ix1 = fmaxf(bx1, px1), iy1 = fmaxf(by1, py1);
            float ix2 = fminf(bx2, px2), iy2 = fminf(by2, py2);
            float inter = fmaxf(ix2 - ix1, 0.0f) * fmaxf(iy2 - iy1, 0.0f);
            float carea = (bx2 - bx1) * (by2 - by1);
            float belong = inter / (carea + 1e-6f);
            sm->belong[k] = belong;
            sm->valid[k] = (belong > BELONG_TH) ? 1 : 0;
        }
    }
    __syncthreads();

    // ---- parent validity combine ----
    if (HAS_PARENT) {
        if (tid == 0) {
            int am = 0, anyvk = 0;
            float bb = -INFINITY;
            for (int k = 0; k < KSEL; ++k) {
                float b = sm->keep[k] ? sm->belong[k] : -INFINITY;
                if (b > bb) { bb = b; am = k; }  // first max (jnp.argmax)
                if (sm->valid[k] && sm->keep[k]) anyvk = 1;
            }
            sm->argm = am;
            sm->anyvk = anyvk;
        }
        __syncthreads();
        if (tid < KSEL) {
            bool valid = sm->anyvk ? (sm->valid[tid] != 0) : (tid == sm->argm);
            sm->nk[tid] = (sm->keep[tid] && valid) ? 1 : 0;
        }
    } else {
        if (tid < KSEL) sm->nk[tid] = sm->keep[tid];
    }
    __syncthreads();

    // ---- sequential NMS, parallel inner loop ----
    for (int i = 0; i < KSEL; ++i) {
        if (tid < KSEL && tid > i && sm->nk[i] && sm->nk[tid]) {
            float x1 = fmaxf(sm->box[i][0], sm->box[tid][0]);
            float y1 = fmaxf(sm->box[i][1], sm->box[tid][1]);
            float x2 = fminf(sm->box[i][2], sm->box[tid][2]);
            float y2 = fminf(sm->box[i][3], sm->box[tid][3]);
            float inter = fmaxf(x2 - x1, 0.0f) * fmaxf(y2 - y1, 0.0f);
            float iou = inter / (sm->area[i] + sm->area[tid] - inter);
            if (iou > NMS_TH) sm->nk[tid] = 0;  // NaN>th == false, matches ref
        }
        __syncthreads();
    }

    // ---- outputs ----
    if (tid < KSEL) {
        const int k = tid;
        const bool nk = sm->nk[k] != 0;
        out_scores[(size_t)img * KSEL + k] = nk ? sm->prob[k] : 0.0f;
        out_keep[(size_t)img * KSEL + k] = nk ? 1.0f : 0.0f;
        if (IS_BEZIER) {
#pragma unroll
            for (int mm = 0; mm < 16; ++mm)
                out_data[((size_t)img * KSEL + k) * 16 + mm] = nk ? sm->data16[k][mm] : 0.0f;
        } else {
#pragma unroll
            for (int mm = 0; mm < 4; ++mm)
                out_data[((size_t)img * KSEL + k) * 4 + mm] = nk ? sm->box[k][mm] : 0.0f;
        }
    }
}

__global__ __launch_bounds__(NTHREADS) void postprocess_kernel(
    const float* __restrict__ blk_logits, const float* __restrict__ lin_logits,
    const float* __restrict__ chr_logits, const float* __restrict__ blk_raw,
    const float* __restrict__ lin_raw, const float* __restrict__ chr_raw,
    const float* __restrict__ tsizes, float* __restrict__ out) {
    __shared__ SharedMem sm;
    const int b = blockIdx.x;
    const int level = b >> 6;  // 64 images per level
    const int img = b & 63;

    // output layout (B=64, K=100): blk(data,sc,kp), lin(data,sc,kp), chr(data16,sc,kp)
    float* blk_data = out + 0;
    float* blk_sc   = out + 25600;
    float* blk_kp   = out + 32000;
    float* lin_data = out + 38400;
    float* lin_sc   = out + 64000;
    float* lin_kp   = out + 70400;
    float* chr_data = out + 76800;
    float* chr_sc   = out + 179200;
    float* chr_kp   = out + 185600;

    if (level == 0) {
        filter_impl<16, false, false>(&sm, blk_logits, blk_raw, nullptr, tsizes,
                                      blk_data, blk_sc, blk_kp, img, 4096, 0, 1);
    } else if (level == 1) {
        filter_impl<64, false, true>(&sm, lin_logits, lin_raw, blk_raw, tsizes,
                                     lin_data, lin_sc, lin_kp, img, 16384, 4096, 4);
    } else {
        filter_impl<64, true, true>(&sm, chr_logits, chr_raw, lin_raw, tsizes,
                                    chr_data, chr_sc, chr_kp, img, 16384, 16384, 1);
    }
}

extern "C" void kernel_launch(void* const* d_in, const int* in_sizes, int n_in,
                              void* d_out, int out_size, void* d_ws, size_t ws_size,
                              hipStream_t stream) {
    (void)in_sizes; (void)n_in; (void)d_ws; (void)ws_size; (void)out_size;
    const float* blk_logits = (const float*)d_in[0];
    const float* lin_logits = (const float*)d_in[1];
    const float* chr_logits = (const float*)d_in[2];
    const float* blk_raw = (const float*)d_in[3];
    const float* lin_raw = (const float*)d_in[4];
    const float* chr_raw = (const float*)d_in[5];
    const float* tsz = (const float*)d_in[6];
    float* out = (float*)d_out;

    hipLaunchKernelGGL(postprocess_kernel, dim3(192), dim3(NTHREADS), 0, stream,
                       blk_logits, lin_logits, chr_logits, blk_raw, lin_raw,
                       chr_raw, tsz, out);
}

// Round 2
// 134.414 us; speedup vs baseline: 2.6052x; 2.6052x over previous
//
#include <hip/hip_runtime.h>
#include <math.h>

#define NTHREADS 256
#define KSEL 100
#define NBINS 2048
#define CAP 1024
#define SCORE_TH 0.1f
#define NMS_TH 0.1f
#define BELONG_TH 0.6f

typedef unsigned long long ull;

// Pack (value, index) so that u64 max == (max value, min index on ties).
__device__ __forceinline__ ull make_key(float f, unsigned gidx) {
    unsigned u = __float_as_uint(f);
    u = (u & 0x80000000u) ? ~u : (u | 0x80000000u);
    return (((ull)u) << 32) | (ull)(0xFFFFFFFFu - gidx);
}
__device__ __forceinline__ float key_val(ull k) {
    unsigned u = (unsigned)(k >> 32);
    u = (u & 0x80000000u) ? (u ^ 0x80000000u) : ~u;
    return __uint_as_float(u);
}
__device__ __forceinline__ unsigned key_idx(ull k) {
    return 0xFFFFFFFFu - (unsigned)(k & 0xFFFFFFFFu);
}
// Monotone non-decreasing map p -> bin. MUST be used identically in the
// histogram and the compaction passes (count consistency is what makes the
// candidate-superset argument exact).
__device__ __forceinline__ int binof(float p) {
    int b = (int)(p * (float)NBINS);
    b = b < 0 ? 0 : (b > NBINS - 1 ? NBINS - 1 : b);
    return b;
}

struct SharedMem {
    union {
        unsigned hist[NBINS];   // phase A
        ull cand[CAP];          // phase B (hist dead by then)
        ull part[4];            // fallback only (cand dead by then)
    } u;
    int bstar;
    int scnt;
    int wsum[4];
    float prob[KSEL];
    int   sidx[KSEL];
    float box[KSEL][4];
    float data16[KSEL][16];
    float area[KSEL];
    float belong[KSEL];
    unsigned char keep[KSEL];
    unsigned char valid[KSEL];
    unsigned char nk[KSEL];
    int argm;
    int anyvk;
};

template <int NPT, bool IS_BEZIER, bool HAS_PARENT>
__device__ void filter_impl(SharedMem* sm,
                            const float* __restrict__ logits,
                            const float* __restrict__ raw,
                            const float* __restrict__ parent_raw,
                            const float* __restrict__ tsizes,
                            float* __restrict__ out_data,
                            float* __restrict__ out_scores,
                            float* __restrict__ out_keep,
                            int img, int N, int PN, int ef) {
    const int tid = threadIdx.x;
    const int lane = tid & 63;
    const int wv = tid >> 6;
    const float* lg = logits + (size_t)img * N;

    // ---- init LDS ----
    for (int i = tid; i < NBINS; i += NTHREADS) sm->u.hist[i] = 0;
    if (tid == 0) sm->scnt = 0;
    __syncthreads();

    // ---- load + sigmoid into registers (fully unrolled -> VGPRs) ----
    float p[NPT];
#pragma unroll
    for (int j = 0; j < NPT; ++j) {
        float x = lg[j * NTHREADS + tid];
        p[j] = 1.0f / (1.0f + expf(-x));
    }

    // ---- histogram of sigmoid values ----
#pragma unroll
    for (int j = 0; j < NPT; ++j)
        atomicAdd(&sm->u.hist[binof(p[j])], 1u);
    __syncthreads();

    // ---- find threshold bin b*: largest b with count(bin >= b) >= KSEL ----
    // thread t owns 8 consecutive bins in DESCENDING order starting 2047-8t
    int c[8];
    int s = 0;
#pragma unroll
    for (int q = 0; q < 8; ++q) {
        c[q] = (int)sm->u.hist[NBINS - 1 - 8 * tid - q];
        s += c[q];
    }
    int vv = s;  // inclusive scan within wave
#pragma unroll
    for (int off = 1; off < 64; off <<= 1) {
        int o = __shfl_up(vv, off, 64);
        if (lane >= off) vv += o;
    }
    if (lane == 63) sm->wsum[wv] = vv;
    __syncthreads();
    int base = 0;
    for (int u2 = 0; u2 < wv; ++u2) base += sm->wsum[u2];
    int run = base + vv - s;  // exclusive prefix (count in all higher bins)
#pragma unroll
    for (int q = 0; q < 8; ++q) {
        int before = run;
        run += c[q];
        if (before < KSEL && run >= KSEL) sm->bstar = NBINS - 1 - 8 * tid - q;
    }
    __syncthreads();
    const int bstar = sm->bstar;

    // ---- compact candidates (bin >= b*) ----
#pragma unroll
    for (int j = 0; j < NPT; ++j) {
        if (binof(p[j]) >= bstar) {
            int pos = atomicAdd(&sm->scnt, 1);
            if (pos < CAP) sm->u.cand[pos] = make_key(p[j], (unsigned)(j * NTHREADS + tid));
        }
    }
    __syncthreads();
    const int cnt = sm->scnt;

    if (cnt <= CAP) {
        // ---- exact rank scatter: rank = #keys strictly greater (keys unique) ----
        for (int t = tid; t < cnt; t += NTHREADS) {
            ull mk = sm->u.cand[t];
            int rank = 0;
            for (int u2 = 0; u2 < cnt; ++u2) rank += (sm->u.cand[u2] > mk) ? 1 : 0;
            if (rank < KSEL) {
                sm->prob[rank] = key_val(mk);
                sm->sidx[rank] = (int)key_idx(mk);
            }
        }
    } else {
        // ---- fallback (degenerate distributions only): serial iterative top-K ----
        ull best = make_key(p[0], (unsigned)tid);
#pragma unroll
        for (int j = 1; j < NPT; ++j) {
            ull kk = make_key(p[j], (unsigned)(j * NTHREADS + tid));
            if (kk > best) best = kk;
        }
        for (int k = 0; k < KSEL; ++k) {
            ull m = best;
#pragma unroll
            for (int off = 32; off > 0; off >>= 1) {
                ull o = __shfl_down(m, off, 64);
                if (o > m) m = o;
            }
            if (lane == 0) sm->u.part[wv] = m;
            __syncthreads();
            ull w = sm->u.part[0];
#pragma unroll
            for (int q = 1; q < 4; ++q)
                if (sm->u.part[q] > w) w = sm->u.part[q];
            if (tid == 0) {
                sm->prob[k] = key_val(w);
                sm->sidx[k] = (int)key_idx(w);
            }
            __syncthreads();
            unsigned gidx = key_idx(w);
            if ((gidx & (NTHREADS - 1)) == (unsigned)tid) {
                int j = (int)(gidx >> 8);
#pragma unroll
                for (int jj = 0; jj < NPT; ++jj)
                    if (jj == j) p[jj] = -INFINITY;
                best = make_key(p[0], (unsigned)tid);
#pragma unroll
                for (int jj = 1; jj < NPT; ++jj) {
                    ull kk = make_key(p[jj], (unsigned)(jj * NTHREADS + tid));
                    if (kk > best) best = kk;
                }
            }
        }
    }
    __syncthreads();

    const float Himg = tsizes[img * 2 + 0];
    const float Wimg = tsizes[img * 2 + 1];

    // ---- per-selected-box decode (threads 0..99) ----
    if (tid < KSEL) {
        const int k = tid;
        const int si = sm->sidx[k];
        const float val = sm->prob[k];
        const bool any = sm->prob[0] > SCORE_TH;  // sorted desc => any == keep[0]
        bool keep = any ? (val > SCORE_TH) : (k == 0);

        float bx1, by1, bx2, by2;
        if (IS_BEZIER) {
            const float* r = raw + ((size_t)img * N + si) * 16;
            float c16[16];
#pragma unroll
            for (int mm = 0; mm < 8; ++mm) {
                c16[2 * mm]     = r[2 * mm]     * Himg;  // tile((h,w),8): even -> h
                c16[2 * mm + 1] = r[2 * mm + 1] * Wimg;  // odd -> w
            }
            float mn0 = INFINITY, mn1 = INFINITY, mx0 = -INFINITY, mx1 = -INFINITY;
            const float step = 1.0f / 9.0f;
#pragma unroll
            for (int sNum = 0; sNum < 10; ++sNum) {
                float t = (float)sNum * step;
                float ti = 1.0f - t;
                float b0 = ti * ti * ti;
                float b1 = 3.0f * t * ti * ti;
                float b2 = 3.0f * t * t * ti;
                float b3 = t * t * t;
#pragma unroll
                for (int cu = 0; cu < 2; ++cu) {
                    const float* cc = c16 + cu * 8;
                    float p0 = b0 * cc[0] + b1 * cc[2] + b2 * cc[4] + b3 * cc[6];
                    float p1 = b0 * cc[1] + b1 * cc[3] + b2 * cc[5] + b3 * cc[7];
                    mn0 = fminf(mn0, p0); mx0 = fmaxf(mx0, p0);
                    mn1 = fminf(mn1, p1); mx1 = fmaxf(mx1, p1);
                }
            }
            bx1 = mn0; by1 = mn1; bx2 = mx0; by2 = mx1;
#pragma unroll
            for (int mm = 0; mm < 16; ++mm) sm->data16[k][mm] = c16[mm];
        } else {
            const float* r = raw + ((size_t)img * N + si) * 4;
            float cx = r[0], cy = r[1], w = r[2], h = r[3];
            bx1 = (cx - 0.5f * w) * Wimg;
            by1 = (cy - 0.5f * h) * Himg;
            bx2 = (cx + 0.5f * w) * Wimg;
            by2 = (cy + 0.5f * h) * Himg;
            if (!HAS_PARENT) {  // block level: clip to [0, (W,H)]
                bx1 = fminf(fmaxf(bx1, 0.0f), Wimg);
                by1 = fminf(fmaxf(by1, 0.0f), Himg);
                bx2 = fminf(fmaxf(bx2, 0.0f), Wimg);
                by2 = fminf(fmaxf(by2, 0.0f), Himg);
            }
        }
        sm->box[k][0] = bx1; sm->box[k][1] = by1;
        sm->box[k][2] = bx2; sm->box[k][3] = by2;
        sm->area[k] = (bx2 - bx1) * (by2 - by1);
        sm->keep[k] = keep ? 1 : 0;

        if (HAS_PARENT) {
            int pi = si / ef;
            const float* pr = parent_raw + ((size_t)img * PN + pi) * 4;
            float pcx = pr[0], pcy = pr[1], pw = pr[2], ph = pr[3];
            float px1 = (pcx - 0.5f * pw) * Wimg;
            float py1 = (pcy - 0.5f * ph) * Himg;
            float px2 = (pcx + 0.5f * pw) * Wimg;
            float py2 = (pcy + 0.5f * ph) * Himg;
            float ix1 = fmaxf(bx1, px1), iy1 = fmaxf(by1, py1);
            float ix2 = fminf(bx2, px2), iy2 = fminf(by2, py2);
            float inter = fmaxf(ix2 - ix1, 0.0f) * fmaxf(iy2 - iy1, 0.0f);
            float carea = (bx2 - bx1) * (by2 - by1);
            float belong = inter / (carea + 1e-6f);
            sm->belong[k] = belong;
            sm->valid[k] = (belong > BELONG_TH) ? 1 : 0;
        }
    }
    __syncthreads();

    // ---- parent validity combine (wave 0) ----
    if (HAS_PARENT) {
        if (tid < 64) {
            ull k0 = make_key(sm->keep[tid] ? sm->belong[tid] : -INFINITY, (unsigned)tid);
            bool p0 = sm->valid[tid] && sm->keep[tid];
            ull k1 = 0;  // loses to any real key
            bool p1 = false;
            if (tid < KSEL - 64) {
                k1 = make_key(sm->keep[tid + 64] ? sm->belong[tid + 64] : -INFINITY,
                              (unsigned)(tid + 64));
                p1 = sm->valid[tid + 64] && sm->keep[tid + 64];
            }
            ull m = k0 > k1 ? k0 : k1;
#pragma unroll
            for (int off = 32; off > 0; off >>= 1) {
                ull o = __shfl_xor(m, off, 64);
                if (o > m) m = o;
            }
            ull bal = __ballot(p0 || p1);
            if (lane == 0) {
                sm->argm = (int)key_idx(m);   // first max (smallest k on ties)
                sm->anyvk = (bal != 0ULL) ? 1 : 0;
            }
        }
        __syncthreads();
        if (tid < KSEL) {
            bool valid = sm->anyvk ? (sm->valid[tid] != 0) : (tid == sm->argm);
            sm->nk[tid] = (sm->keep[tid] && valid) ? 1 : 0;
        }
    } else {
        if (tid < KSEL) sm->nk[tid] = sm->keep[tid];
    }
    __syncthreads();

    // ---- greedy NMS on wave 0: lane l owns boxes l and l+64, keep mask
    //      replicated per-lane as 2x u64, suppression via ballot. 0 barriers. ----
    if (tid < 64) {
        const int l = tid;
        float s0x1 = sm->box[l][0], s0y1 = sm->box[l][1];
        float s0x2 = sm->box[l][2], s0y2 = sm->box[l][3];
        float s0a = sm->area[l];
        float s1x1 = 0.f, s1y1 = 0.f, s1x2 = 0.f, s1y2 = 0.f, s1a = 0.f;
        if (l < KSEL - 64) {
            s1x1 = sm->box[l + 64][0]; s1y1 = sm->box[l + 64][1];
            s1x2 = sm->box[l + 64][2]; s1y2 = sm->box[l + 64][3];
            s1a = sm->area[l + 64];
        }
        ull keepLo = __ballot(sm->nk[l] != 0);
        ull keepHi = __ballot((l < KSEL - 64) && (sm->nk[l + 64] != 0));
        for (int i = 0; i < KSEL; ++i) {
            bool ki = (i < 64) ? (((keepLo >> i) & 1ULL) != 0)
                               : (((keepHi >> (i - 64)) & 1ULL) != 0);
            if (!ki) continue;  // uniform branch (masks replicated)
            float bx1, by1, bx2, by2, ba;
            if (i < 64) {
                bx1 = __shfl(s0x1, i, 64); by1 = __shfl(s0y1, i, 64);
                bx2 = __shfl(s0x2, i, 64); by2 = __shfl(s0y2, i, 64);
                ba = __shfl(s0a, i, 64);
            } else {
                int ii = i - 64;
                bx1 = __shfl(s1x1, ii, 64); by1 = __shfl(s1y1, ii, 64);
                bx2 = __shfl(s1x2, ii, 64); by2 = __shfl(s1y2, ii, 64);
                ba = __shfl(s1a, ii, 64);
            }
            // slot 0 (box j = l)
            float ix1 = fmaxf(bx1, s0x1), iy1 = fmaxf(by1, s0y1);
            float ix2 = fminf(bx2, s0x2), iy2 = fminf(by2, s0y2);
            float in0 = fmaxf(ix2 - ix1, 0.0f) * fmaxf(iy2 - iy1, 0.0f);
            float iou0 = in0 / (ba + s0a - in0);
            bool sup0 = (l > i) && (iou0 > NMS_TH);  // NaN>th == false
            // slot 1 (box j = l + 64; dummy for l >= 36 only pollutes unused bits)
            float jx1 = fmaxf(bx1, s1x1), jy1 = fmaxf(by1, s1y1);
            float jx2 = fminf(bx2, s1x2), jy2 = fminf(by2, s1y2);
            float in1 = fmaxf(jx2 - jx1, 0.0f) * fmaxf(jy2 - jy1, 0.0f);
            float iou1 = in1 / (ba + s1a - in1);
            bool sup1 = ((l + 64) > i) && (iou1 > NMS_TH);
            keepLo &= ~__ballot(sup0);
            keepHi &= ~__ballot(sup1);
        }
        sm->nk[l] = (unsigned char)((keepLo >> l) & 1ULL);
        if (l < KSEL - 64) sm->nk[l + 64] = (unsigned char)((keepHi >> l) & 1ULL);
    }
    __syncthreads();

    // ---- outputs ----
    if (tid < KSEL) {
        const int k = tid;
        const bool nk = sm->nk[k] != 0;
        out_scores[(size_t)img * KSEL + k] = nk ? sm->prob[k] : 0.0f;
        out_keep[(size_t)img * KSEL + k] = nk ? 1.0f : 0.0f;
        if (IS_BEZIER) {
#pragma unroll
            for (int mm = 0; mm < 16; ++mm)
                out_data[((size_t)img * KSEL + k) * 16 + mm] = nk ? sm->data16[k][mm] : 0.0f;
        } else {
#pragma unroll
            for (int mm = 0; mm < 4; ++mm)
                out_data[((size_t)img * KSEL + k) * 4 + mm] = nk ? sm->box[k][mm] : 0.0f;
        }
    }
}

__global__ __launch_bounds__(NTHREADS) void postprocess_kernel(
    const float* __restrict__ blk_logits, const float* __restrict__ lin_logits,
    const float* __restrict__ chr_logits, const float* __restrict__ blk_raw,
    const float* __restrict__ lin_raw, const float* __restrict__ chr_raw,
    const float* __restrict__ tsizes, float* __restrict__ out) {
    __shared__ SharedMem sm;
    const int b = blockIdx.x;
    const int level = b >> 6;  // 64 images per level
    const int img = b & 63;

    // output layout (B=64, K=100): blk(data,sc,kp), lin(data,sc,kp), chr(data16,sc,kp)
    float* blk_data = out + 0;
    float* blk_sc   = out + 25600;
    float* blk_kp   = out + 32000;
    float* lin_data = out + 38400;
    float* lin_sc   = out + 64000;
    float* lin_kp   = out + 70400;
    float* chr_data = out + 76800;
    float* chr_sc   = out + 179200;
    float* chr_kp   = out + 185600;

    if (level == 0) {
        filter_impl<16, false, false>(&sm, blk_logits, blk_raw, nullptr, tsizes,
                                      blk_data, blk_sc, blk_kp, img, 4096, 0, 1);
    } else if (level == 1) {
        filter_impl<64, false, true>(&sm, lin_logits, lin_raw, blk_raw, tsizes,
                                     lin_data, lin_sc, lin_kp, img, 16384, 4096, 4);
    } else {
        filter_impl<64, true, true>(&sm, chr_logits, chr_raw, lin_raw, tsizes,
                                    chr_data, chr_sc, chr_kp, img, 16384, 16384, 1);
    }
}

extern "C" void kernel_launch(void* const* d_in, const int* in_sizes, int n_in,
                              void* d_out, int out_size, void* d_ws, size_t ws_size,
                              hipStream_t stream) {
    (void)in_sizes; (void)n_in; (void)d_ws; (void)ws_size; (void)out_size;
    const float* blk_logits = (const float*)d_in[0];
    const float* lin_logits = (const float*)d_in[1];
    const float* chr_logits = (const float*)d_in[2];
    const float* blk_raw = (const float*)d_in[3];
    const float* lin_raw = (const float*)d_in[4];
    const float* chr_raw = (const float*)d_in[5];
    const float* tsz = (const float*)d_in[6];
    float* out = (float*)d_out;

    hipLaunchKernelGGL(postprocess_kernel, dim3(192), dim3(NTHREADS), 0, stream,
                       blk_logits, lin_logits, chr_logits, blk_raw, lin_raw,
                       chr_raw, tsz, out);
}

// Round 3
// 131.752 us; speedup vs baseline: 2.6578x; 1.0202x over previous
//
#include <hip/hip_runtime.h>
#include <math.h>

#define NTHREADS 1024
#define NWAVES 16
#define KSEL 100
#define NBINS 2048
#define CAP 1024
#define SCORE_TH 0.1f
#define NMS_TH 0.1f
#define BELONG_TH 0.6f

typedef unsigned long long ull;

// Pack (value, index) so that u64 max == (max value, min index on ties).
__device__ __forceinline__ ull make_key(float f, unsigned gidx) {
    unsigned u = __float_as_uint(f);
    u = (u & 0x80000000u) ? ~u : (u | 0x80000000u);
    return (((ull)u) << 32) | (ull)(0xFFFFFFFFu - gidx);
}
__device__ __forceinline__ float key_val(ull k) {
    unsigned u = (unsigned)(k >> 32);
    u = (u & 0x80000000u) ? (u ^ 0x80000000u) : ~u;
    return __uint_as_float(u);
}
__device__ __forceinline__ unsigned key_idx(ull k) {
    return 0xFFFFFFFFu - (unsigned)(k & 0xFFFFFFFFu);
}
// Monotone map p -> bin; used identically in histogram and compaction.
__device__ __forceinline__ int binof(float p) {
    int b = (int)(p * (float)NBINS);
    b = b < 0 ? 0 : (b > NBINS - 1 ? NBINS - 1 : b);
    return b;
}
// element e of this thread -> global index (float4 load layout)
__device__ __forceinline__ unsigned gidx_of(int e, int tid) {
    return ((unsigned)(e >> 2)) * (NTHREADS * 4) + ((unsigned)tid << 2) + (unsigned)(e & 3);
}

struct SharedMem {
    union {
        unsigned hist[NBINS];   // phase A
        ull cand[CAP];          // phase B (hist dead by then)
        ull part[NWAVES];       // fallback only
    } u;
    int bstar;
    int scnt;
    int wsum[NWAVES];
    float prob[KSEL];
    int   sidx[KSEL];
    alignas(16) float box[KSEL][4];
    float data16[KSEL][16];
    float area[KSEL];
    float belong[KSEL];
    ull nmsrow[KSEL][2];
    unsigned char keep[KSEL];
    unsigned char valid[KSEL];
    unsigned char nk[KSEL];
    int argm;
    int anyvk;
};

template <int NPT, bool IS_BEZIER, bool HAS_PARENT>
__device__ void filter_impl(SharedMem* sm,
                            const float* __restrict__ logits,
                            const float* __restrict__ raw,
                            const float* __restrict__ parent_raw,
                            const float* __restrict__ tsizes,
                            float* __restrict__ out_data,
                            float* __restrict__ out_scores,
                            float* __restrict__ out_keep,
                            int img, int N, int PN, int ef) {
    const int tid = threadIdx.x;
    const int lane = tid & 63;
    const int wv = tid >> 6;
    const float* lg = logits + (size_t)img * N;

    // ---- init LDS ----
#pragma unroll
    for (int i = tid; i < NBINS; i += NTHREADS) sm->u.hist[i] = 0;
    if (tid == 0) sm->scnt = 0;
    __syncthreads();

    // ---- vectorized load + sigmoid into registers ----
    float p[NPT];
    const float4* lg4 = (const float4*)lg;
#pragma unroll
    for (int v = 0; v < NPT / 4; ++v) {
        float4 x = lg4[v * NTHREADS + tid];
        p[4 * v + 0] = 1.0f / (1.0f + expf(-x.x));
        p[4 * v + 1] = 1.0f / (1.0f + expf(-x.y));
        p[4 * v + 2] = 1.0f / (1.0f + expf(-x.z));
        p[4 * v + 3] = 1.0f / (1.0f + expf(-x.w));
    }

    // ---- histogram of sigmoid values ----
#pragma unroll
    for (int j = 0; j < NPT; ++j)
        atomicAdd(&sm->u.hist[binof(p[j])], 1u);
    __syncthreads();

    // ---- find threshold bin b*: largest b with count(bin >= b) >= KSEL ----
    // thread t owns 2 consecutive bins in DESCENDING order
    int c0 = (int)sm->u.hist[NBINS - 1 - 2 * tid];
    int c1 = (int)sm->u.hist[NBINS - 2 - 2 * tid];
    int s = c0 + c1;
    int vv = s;  // inclusive scan within wave
#pragma unroll
    for (int off = 1; off < 64; off <<= 1) {
        int o = __shfl_up(vv, off, 64);
        if (lane >= off) vv += o;
    }
    if (lane == 63) sm->wsum[wv] = vv;
    __syncthreads();
    int base = 0;
#pragma unroll
    for (int u2 = 0; u2 < NWAVES; ++u2) base += (u2 < wv) ? sm->wsum[u2] : 0;
    int run = base + vv - s;  // count in all strictly-higher bins
    if (run < KSEL && run + c0 >= KSEL) sm->bstar = NBINS - 1 - 2 * tid;
    int run2 = run + c0;
    if (run2 < KSEL && run2 + c1 >= KSEL) sm->bstar = NBINS - 2 - 2 * tid;
    __syncthreads();
    const int bstar = sm->bstar;

    // ---- compact candidates (bin >= b*) ----
#pragma unroll
    for (int j = 0; j < NPT; ++j) {
        if (binof(p[j]) >= bstar) {
            int pos = atomicAdd(&sm->scnt, 1);
            if (pos < CAP) sm->u.cand[pos] = make_key(p[j], gidx_of(j, tid));
        }
    }
    __syncthreads();
    const int cnt = sm->scnt;

    if (cnt <= CAP) {
        // ---- exact rank scatter: rank = #keys strictly greater (keys unique) ----
        for (int t = tid; t < cnt; t += NTHREADS) {
            ull mk = sm->u.cand[t];
            int rank = 0;
            for (int u2 = 0; u2 < cnt; ++u2) rank += (sm->u.cand[u2] > mk) ? 1 : 0;
            if (rank < KSEL) {
                sm->prob[rank] = key_val(mk);
                sm->sidx[rank] = (int)key_idx(mk);
            }
        }
    } else {
        // ---- fallback (degenerate distributions): serial iterative top-K ----
        ull best = make_key(p[0], gidx_of(0, tid));
#pragma unroll
        for (int j = 1; j < NPT; ++j) {
            ull kk = make_key(p[j], gidx_of(j, tid));
            if (kk > best) best = kk;
        }
        for (int k = 0; k < KSEL; ++k) {
            ull m = best;
#pragma unroll
            for (int off = 32; off > 0; off >>= 1) {
                ull o = __shfl_down(m, off, 64);
                if (o > m) m = o;
            }
            if (lane == 0) sm->u.part[wv] = m;
            __syncthreads();
            ull w = sm->u.part[0];
#pragma unroll
            for (int q = 1; q < NWAVES; ++q)
                if (sm->u.part[q] > w) w = sm->u.part[q];
            if (tid == 0) {
                sm->prob[k] = key_val(w);
                sm->sidx[k] = (int)key_idx(w);
            }
            __syncthreads();
            unsigned gidx = key_idx(w);
            if (((gidx >> 2) & (NTHREADS - 1)) == (unsigned)tid) {
                int e = (int)(((gidx >> 12) << 2) | (gidx & 3));
#pragma unroll
                for (int jj = 0; jj < NPT; ++jj)
                    if (jj == e) p[jj] = -INFINITY;
                best = make_key(p[0], gidx_of(0, tid));
#pragma unroll
                for (int jj = 1; jj < NPT; ++jj) {
                    ull kk = make_key(p[jj], gidx_of(jj, tid));
                    if (kk > best) best = kk;
                }
            }
        }
    }
    __syncthreads();

    const float Himg = tsizes[img * 2 + 0];
    const float Wimg = tsizes[img * 2 + 1];

    // ---- per-selected-box decode (threads 0..99) ----
    if (tid < KSEL) {
        const int k = tid;
        const int si = sm->sidx[k];
        const float val = sm->prob[k];
        const bool any = sm->prob[0] > SCORE_TH;  // sorted desc => any == keep[0]
        bool keep = any ? (val > SCORE_TH) : (k == 0);

        float bx1, by1, bx2, by2;
        if (IS_BEZIER) {
            const float4* r4 = (const float4*)(raw + ((size_t)img * N + si) * 16);
            float c16[16];
#pragma unroll
            for (int v = 0; v < 4; ++v) {
                float4 x = r4[v];
                c16[4 * v + 0] = x.x * Himg;  // tile((h,w),8): even -> h
                c16[4 * v + 1] = x.y * Wimg;  // odd -> w
                c16[4 * v + 2] = x.z * Himg;
                c16[4 * v + 3] = x.w * Wimg;
            }
            float mn0 = INFINITY, mn1 = INFINITY, mx0 = -INFINITY, mx1 = -INFINITY;
            const float step = 1.0f / 9.0f;
#pragma unroll
            for (int sNum = 0; sNum < 10; ++sNum) {
                float t = (float)sNum * step;
                float ti = 1.0f - t;
                float b0 = ti * ti * ti;
                float b1 = 3.0f * t * ti * ti;
                float b2 = 3.0f * t * t * ti;
                float b3 = t * t * t;
#pragma unroll
                for (int cu = 0; cu < 2; ++cu) {
                    const float* cc = c16 + cu * 8;
                    float p0 = b0 * cc[0] + b1 * cc[2] + b2 * cc[4] + b3 * cc[6];
                    float p1 = b0 * cc[1] + b1 * cc[3] + b2 * cc[5] + b3 * cc[7];
                    mn0 = fminf(mn0, p0); mx0 = fmaxf(mx0, p0);
                    mn1 = fminf(mn1, p1); mx1 = fmaxf(mx1, p1);
                }
            }
            bx1 = mn0; by1 = mn1; bx2 = mx0; by2 = mx1;
#pragma unroll
            for (int mm = 0; mm < 16; ++mm) sm->data16[k][mm] = c16[mm];
        } else {
            float4 r = *(const float4*)(raw + ((size_t)img * N + si) * 4);
            float cx = r.x, cy = r.y, w = r.z, h = r.w;
            bx1 = (cx - 0.5f * w) * Wimg;
            by1 = (cy - 0.5f * h) * Himg;
            bx2 = (cx + 0.5f * w) * Wimg;
            by2 = (cy + 0.5f * h) * Himg;
            if (!HAS_PARENT) {  // block level: clip to [0, (W,H)]
                bx1 = fminf(fmaxf(bx1, 0.0f), Wimg);
                by1 = fminf(fmaxf(by1, 0.0f), Himg);
                bx2 = fminf(fmaxf(bx2, 0.0f), Wimg);
                by2 = fminf(fmaxf(by2, 0.0f), Himg);
            }
        }
        sm->box[k][0] = bx1; sm->box[k][1] = by1;
        sm->box[k][2] = bx2; sm->box[k][3] = by2;
        sm->area[k] = (bx2 - bx1) * (by2 - by1);
        sm->keep[k] = keep ? 1 : 0;

        if (HAS_PARENT) {
            int pi = si / ef;
            float4 pr = *(const float4*)(parent_raw + ((size_t)img * PN + pi) * 4);
            float px1 = (pr.x - 0.5f * pr.z) * Wimg;
            float py1 = (pr.y - 0.5f * pr.w) * Himg;
            float px2 = (pr.x + 0.5f * pr.z) * Wimg;
            float py2 = (pr.y + 0.5f * pr.w) * Himg;
            float ix1 = fmaxf(bx1, px1), iy1 = fmaxf(by1, py1);
            float ix2 = fminf(bx2, px2), iy2 = fminf(by2, py2);
            float inter = fmaxf(ix2 - ix1, 0.0f) * fmaxf(iy2 - iy1, 0.0f);
            float carea = (bx2 - bx1) * (by2 - by1);
            float belong = inter / (carea + 1e-6f);
            sm->belong[k] = belong;
            sm->valid[k] = (belong > BELONG_TH) ? 1 : 0;
        }
    }
    __syncthreads();

    // ---- parent validity combine (wave 0) ----
    if (HAS_PARENT) {
        if (tid < 64) {
            ull k0 = make_key(sm->keep[tid] ? sm->belong[tid] : -INFINITY, (unsigned)tid);
            bool p0 = sm->valid[tid] && sm->keep[tid];
            ull k1 = 0;
            bool p1 = false;
            if (tid < KSEL - 64) {
                k1 = make_key(sm->keep[tid + 64] ? sm->belong[tid + 64] : -INFINITY,
                              (unsigned)(tid + 64));
                p1 = sm->valid[tid + 64] && sm->keep[tid + 64];
            }
            ull m = k0 > k1 ? k0 : k1;
#pragma unroll
            for (int off = 32; off > 0; off >>= 1) {
                ull o = __shfl_xor(m, off, 64);
                if (o > m) m = o;
            }
            ull bal = __ballot(p0 || p1);
            if (lane == 0) {
                sm->argm = (int)key_idx(m);   // first max (smallest k on ties)
                sm->anyvk = (bal != 0ULL) ? 1 : 0;
            }
        }
        __syncthreads();
        if (tid < KSEL) {
            bool valid = sm->anyvk ? (sm->valid[tid] != 0) : (tid == sm->argm);
            sm->nk[tid] = (sm->keep[tid] && valid) ? 1 : 0;
        }
    } else {
        if (tid < KSEL) sm->nk[tid] = sm->keep[tid];
    }
    __syncthreads();

    // ---- NMS phase 1: build 100x128 suppression bit-matrix in parallel.
    //      row i bit j = (iou(i,j) > TH) && (j > i). All 16 waves participate. ----
    {
        float4 b0 = *(const float4*)sm->box[lane];
        float a0 = sm->area[lane];
        float4 b1 = make_float4(0.f, 0.f, 0.f, 0.f);
        float a1 = 0.f;
        if (lane < KSEL - 64) {
            b1 = *(const float4*)sm->box[lane + 64];
            a1 = sm->area[lane + 64];
        }
        for (int i = wv; i < KSEL; i += NWAVES) {
            float rx1, ry1, rx2, ry2, ra;
            if (i < 64) {
                rx1 = __shfl(b0.x, i, 64); ry1 = __shfl(b0.y, i, 64);
                rx2 = __shfl(b0.z, i, 64); ry2 = __shfl(b0.w, i, 64);
                ra  = __shfl(a0, i, 64);
            } else {
                rx1 = __shfl(b1.x, i - 64, 64); ry1 = __shfl(b1.y, i - 64, 64);
                rx2 = __shfl(b1.z, i - 64, 64); ry2 = __shfl(b1.w, i - 64, 64);
                ra  = __shfl(a1, i - 64, 64);
            }
            // slot 0: j = lane
            float ix1 = fmaxf(rx1, b0.x), iy1 = fmaxf(ry1, b0.y);
            float ix2 = fminf(rx2, b0.z), iy2 = fminf(ry2, b0.w);
            float in0 = fmaxf(ix2 - ix1, 0.0f) * fmaxf(iy2 - iy1, 0.0f);
            float iou0 = in0 / (ra + a0 - in0);
            bool sup0 = (lane > i) && (iou0 > NMS_TH);  // NaN>th == false
            // slot 1: j = lane + 64
            float jx1 = fmaxf(rx1, b1.x), jy1 = fmaxf(ry1, b1.y);
            float jx2 = fminf(rx2, b1.z), jy2 = fminf(ry2, b1.w);
            float in1 = fmaxf(jx2 - jx1, 0.0f) * fmaxf(jy2 - jy1, 0.0f);
            float iou1 = in1 / (ra + a1 - in1);
            bool sup1 = (lane < KSEL - 64) && ((lane + 64) > i) && (iou1 > NMS_TH);
            ull w0 = __ballot(sup0);
            ull w1 = __ballot(sup1);
            if (lane == 0) { sm->nmsrow[i][0] = w0; sm->nmsrow[i][1] = w1; }
        }
    }
    __syncthreads();

    // ---- NMS phase 2: sequential mask sweep on wave 0 (branchless, 0 barriers) ----
    if (tid < 64) {
        const int l = lane;
        ull r0lo = sm->nmsrow[l][0], r0hi = sm->nmsrow[l][1];
        ull r1lo = 0, r1hi = 0;
        if (l < KSEL - 64) { r1lo = sm->nmsrow[l + 64][0]; r1hi = sm->nmsrow[l + 64][1]; }
        ull keepLo = __ballot(sm->nk[l] != 0);
        ull keepHi = __ballot((l < KSEL - 64) && (sm->nk[l + 64] != 0));
#pragma unroll
        for (int i = 0; i < KSEL; ++i) {
            bool ki = (i < 64) ? (((keepLo >> i) & 1ULL) != 0)
                               : (((keepHi >> (i - 64)) & 1ULL) != 0);
            ull slo = (i < 64) ? __shfl(r0lo, i, 64) : __shfl(r1lo, i - 64, 64);
            ull shi = (i < 64) ? __shfl(r0hi, i, 64) : __shfl(r1hi, i - 64, 64);
            keepLo &= ki ? ~slo : ~0ULL;
            keepHi &= ki ? ~shi : ~0ULL;
        }
        sm->nk[l] = (unsigned char)((keepLo >> l) & 1ULL);
        if (l < KSEL - 64) sm->nk[l + 64] = (unsigned char)((keepHi >> l) & 1ULL);
    }
    __syncthreads();

    // ---- outputs ----
    if (tid < KSEL) {
        const int k = tid;
        const bool nk = sm->nk[k] != 0;
        out_scores[(size_t)img * KSEL + k] = nk ? sm->prob[k] : 0.0f;
        out_keep[(size_t)img * KSEL + k] = nk ? 1.0f : 0.0f;
        if (IS_BEZIER) {
#pragma unroll
            for (int mm = 0; mm < 16; ++mm)
                out_data[((size_t)img * KSEL + k) * 16 + mm] = nk ? sm->data16[k][mm] : 0.0f;
        } else {
#pragma unroll
            for (int mm = 0; mm < 4; ++mm)
                out_data[((size_t)img * KSEL + k) * 4 + mm] = nk ? sm->box[k][mm] : 0.0f;
        }
    }
}

__global__ __launch_bounds__(NTHREADS) void postprocess_kernel(
    const float* __restrict__ blk_logits, const float* __restrict__ lin_logits,
    const float* __restrict__ chr_logits, const float* __restrict__ blk_raw,
    const float* __restrict__ lin_raw, const float* __restrict__ chr_raw,
    const float* __restrict__ tsizes, float* __restrict__ out) {
    __shared__ SharedMem sm;
    const int b = blockIdx.x;
    const int level = b >> 6;  // 64 images per level
    const int img = b & 63;

    // output layout (B=64, K=100): blk(data,sc,kp), lin(data,sc,kp), chr(data16,sc,kp)
    float* blk_data = out + 0;
    float* blk_sc   = out + 25600;
    float* blk_kp   = out + 32000;
    float* lin_data = out + 38400;
    float* lin_sc   = out + 64000;
    float* lin_kp   = out + 70400;
    float* chr_data = out + 76800;
    float* chr_sc   = out + 179200;
    float* chr_kp   = out + 185600;

    if (level == 0) {
        filter_impl<4, false, false>(&sm, blk_logits, blk_raw, nullptr, tsizes,
                                     blk_data, blk_sc, blk_kp, img, 4096, 0, 1);
    } else if (level == 1) {
        filter_impl<16, false, true>(&sm, lin_logits, lin_raw, blk_raw, tsizes,
                                     lin_data, lin_sc, lin_kp, img, 16384, 4096, 4);
    } else {
        filter_impl<16, true, true>(&sm, chr_logits, chr_raw, lin_raw, tsizes,
                                    chr_data, chr_sc, chr_kp, img, 16384, 16384, 1);
    }
}

extern "C" void kernel_launch(void* const* d_in, const int* in_sizes, int n_in,
                              void* d_out, int out_size, void* d_ws, size_t ws_size,
                              hipStream_t stream) {
    (void)in_sizes; (void)n_in; (void)d_ws; (void)ws_size; (void)out_size;
    const float* blk_logits = (const float*)d_in[0];
    const float* lin_logits = (const float*)d_in[1];
    const float* chr_logits = (const float*)d_in[2];
    const float* blk_raw = (const float*)d_in[3];
    const float* lin_raw = (const float*)d_in[4];
    const float* chr_raw = (const float*)d_in[5];
    const float* tsz = (const float*)d_in[6];
    float* out = (float*)d_out;

    hipLaunchKernelGGL(postprocess_kernel, dim3(192), dim3(NTHREADS), 0, stream,
                       blk_logits, lin_logits, chr_logits, blk_raw, lin_raw,
                       chr_raw, tsz, out);
}

// Round 4
// 130.101 us; speedup vs baseline: 2.6916x; 1.0127x over previous
//
#include <hip/hip_runtime.h>
#include <math.h>

#define NTHREADS 1024
#define NWAVES 16
#define KSEL 100
#define NBINS 2048
#define CAP 1024
#define SCORE_TH 0.1f
#define NMS_TH 0.1f
#define BELONG_TH 0.6f

typedef unsigned long long ull;

// Pack (value, index) so that u64 max == (max value, min index on ties).
__device__ __forceinline__ ull make_key(float f, unsigned gidx) {
    unsigned u = __float_as_uint(f);
    u = (u & 0x80000000u) ? ~u : (u | 0x80000000u);
    return (((ull)u) << 32) | (ull)(0xFFFFFFFFu - gidx);
}
__device__ __forceinline__ float key_val(ull k) {
    unsigned u = (unsigned)(k >> 32);
    u = (u & 0x80000000u) ? (u ^ 0x80000000u) : ~u;
    return __uint_as_float(u);
}
__device__ __forceinline__ unsigned key_idx(ull k) {
    return 0xFFFFFFFFu - (unsigned)(k & 0xFFFFFFFFu);
}
__device__ __forceinline__ float sigmoidf(float x) {
    return 1.0f / (1.0f + expf(-x));
}
// Monotone map p -> bin; used identically in histogram and compaction passes.
__device__ __forceinline__ int binof(float p) {
    int b = (int)(p * (float)NBINS);
    b = b < 0 ? 0 : (b > NBINS - 1 ? NBINS - 1 : b);
    return b;
}

struct SharedMem {
    union {
        unsigned hist[NBINS];   // phase A
        ull cand[CAP];          // phase B (hist dead by then)
        ull part[NWAVES];       // fallback only (cand dead by then)
    } u;
    int bstar;
    int scnt;
    int wsum[NWAVES];
    float prob[KSEL];
    int   sidx[KSEL];
    alignas(16) float box[KSEL][4];
    float data16[KSEL][16];
    float area[KSEL];
    float belong[KSEL];
    ull nmsrow[KSEL][2];
    unsigned char keep[KSEL];
    unsigned char valid[KSEL];
    unsigned char nk[KSEL];
    int argm;
    int anyvk;
};

template <int NPT, bool IS_BEZIER, bool HAS_PARENT>
__device__ void filter_impl(SharedMem* sm,
                            const float* __restrict__ logits,
                            const float* __restrict__ raw,
                            const float* __restrict__ parent_raw,
                            const float* __restrict__ tsizes,
                            float* __restrict__ out_data,
                            float* __restrict__ out_scores,
                            float* __restrict__ out_keep,
                            int img, int N, int PN, int ef) {
    const int tid = threadIdx.x;
    const int lane = tid & 63;
    const int wv = tid >> 6;
    const float* lg = logits + (size_t)img * N;
    const float4* lg4 = (const float4*)lg;

    // ---- init LDS ----
#pragma unroll
    for (int i = tid; i < NBINS; i += NTHREADS) sm->u.hist[i] = 0;
    if (tid == 0) sm->scnt = 0;
    __syncthreads();

    // ---- pass A: load + sigmoid + histogram (no values retained) ----
#pragma unroll
    for (int v = 0; v < NPT / 4; ++v) {
        float4 x = lg4[v * NTHREADS + tid];
        atomicAdd(&sm->u.hist[binof(sigmoidf(x.x))], 1u);
        atomicAdd(&sm->u.hist[binof(sigmoidf(x.y))], 1u);
        atomicAdd(&sm->u.hist[binof(sigmoidf(x.z))], 1u);
        atomicAdd(&sm->u.hist[binof(sigmoidf(x.w))], 1u);
    }
    __syncthreads();

    // ---- find threshold bin b*: largest b with count(bin >= b) >= KSEL ----
    // thread t owns 2 consecutive bins in DESCENDING order
    int c0 = (int)sm->u.hist[NBINS - 1 - 2 * tid];
    int c1 = (int)sm->u.hist[NBINS - 2 - 2 * tid];
    int s = c0 + c1;
    int vv = s;  // inclusive scan within wave
#pragma unroll
    for (int off = 1; off < 64; off <<= 1) {
        int o = __shfl_up(vv, off, 64);
        if (lane >= off) vv += o;
    }
    if (lane == 63) sm->wsum[wv] = vv;
    __syncthreads();
    int base = 0;
#pragma unroll
    for (int u2 = 0; u2 < NWAVES; ++u2) base += (u2 < wv) ? sm->wsum[u2] : 0;
    int run = base + vv - s;  // count in all strictly-higher bins
    if (run < KSEL && run + c0 >= KSEL) sm->bstar = NBINS - 1 - 2 * tid;
    int run2 = run + c0;
    if (run2 < KSEL && run2 + c1 >= KSEL) sm->bstar = NBINS - 2 - 2 * tid;
    __syncthreads();
    const int bstar = sm->bstar;

    // ---- pass B: reload (L2-hot), recompute identical sigmoid, compact ----
#pragma unroll
    for (int v = 0; v < NPT / 4; ++v) {
        float4 x = lg4[v * NTHREADS + tid];
        float q[4] = {sigmoidf(x.x), sigmoidf(x.y), sigmoidf(x.z), sigmoidf(x.w)};
#pragma unroll
        for (int j = 0; j < 4; ++j) {
            if (binof(q[j]) >= bstar) {
                int pos = atomicAdd(&sm->scnt, 1);
                unsigned gidx = (unsigned)(v * (NTHREADS * 4) + tid * 4 + j);
                if (pos < CAP) sm->u.cand[pos] = make_key(q[j], gidx);
            }
        }
    }
    __syncthreads();
    const int cnt = sm->scnt;

    if (cnt <= CAP) {
        // ---- exact rank scatter: rank = #keys strictly greater (keys unique) ----
        for (int t = tid; t < cnt; t += NTHREADS) {
            ull mk = sm->u.cand[t];
            int rank = 0;
            for (int u2 = 0; u2 < cnt; ++u2) rank += (sm->u.cand[u2] > mk) ? 1 : 0;
            if (rank < KSEL) {
                sm->prob[rank] = key_val(mk);
                sm->sidx[rank] = (int)key_idx(mk);
            }
        }
        __syncthreads();
    } else {
        // ---- fallback (degenerate distributions only): register-free
        //      threshold descent — iteration k picks max key strictly < prev ----
        ull prev = ~0ULL;
        for (int k = 0; k < KSEL; ++k) {
            ull best = 0;
#pragma unroll
            for (int v = 0; v < NPT / 4; ++v) {
                float4 x = lg4[v * NTHREADS + tid];
                float q[4] = {sigmoidf(x.x), sigmoidf(x.y), sigmoidf(x.z), sigmoidf(x.w)};
#pragma unroll
                for (int j = 0; j < 4; ++j) {
                    ull kk = make_key(q[j], (unsigned)(v * (NTHREADS * 4) + tid * 4 + j));
                    if (kk < prev && kk > best) best = kk;
                }
            }
#pragma unroll
            for (int off = 32; off > 0; off >>= 1) {
                ull o = __shfl_down(best, off, 64);
                if (o > best) best = o;
            }
            if (lane == 0) sm->u.part[wv] = best;
            __syncthreads();
            ull w = sm->u.part[0];
#pragma unroll
            for (int q2 = 1; q2 < NWAVES; ++q2)
                if (sm->u.part[q2] > w) w = sm->u.part[q2];
            if (tid == 0) {
                sm->prob[k] = key_val(w);
                sm->sidx[k] = (int)key_idx(w);
            }
            prev = w;
            __syncthreads();  // part[] reuse next iteration
        }
    }

    const float Himg = tsizes[img * 2 + 0];
    const float Wimg = tsizes[img * 2 + 1];

    // ---- per-selected-box decode (threads 0..99) ----
    if (tid < KSEL) {
        const int k = tid;
        const int si = sm->sidx[k];
        const float val = sm->prob[k];
        const bool any = sm->prob[0] > SCORE_TH;  // sorted desc => any == keep[0]
        bool keep = any ? (val > SCORE_TH) : (k == 0);

        float bx1, by1, bx2, by2;
        if (IS_BEZIER) {
            const float4* r4 = (const float4*)(raw + ((size_t)img * N + si) * 16);
            float c16[16];
#pragma unroll
            for (int v = 0; v < 4; ++v) {
                float4 x = r4[v];
                c16[4 * v + 0] = x.x * Himg;  // tile((h,w),8): even -> h
                c16[4 * v + 1] = x.y * Wimg;  // odd -> w
                c16[4 * v + 2] = x.z * Himg;
                c16[4 * v + 3] = x.w * Wimg;
            }
            float mn0 = INFINITY, mn1 = INFINITY, mx0 = -INFINITY, mx1 = -INFINITY;
            const float step = 1.0f / 9.0f;
#pragma unroll
            for (int sNum = 0; sNum < 10; ++sNum) {
                float t = (float)sNum * step;
                float ti = 1.0f - t;
                float b0 = ti * ti * ti;
                float b1 = 3.0f * t * ti * ti;
                float b2 = 3.0f * t * t * ti;
                float b3 = t * t * t;
#pragma unroll
                for (int cu = 0; cu < 2; ++cu) {
                    const float* cc = c16 + cu * 8;
                    float p0 = b0 * cc[0] + b1 * cc[2] + b2 * cc[4] + b3 * cc[6];
                    float p1 = b0 * cc[1] + b1 * cc[3] + b2 * cc[5] + b3 * cc[7];
                    mn0 = fminf(mn0, p0); mx0 = fmaxf(mx0, p0);
                    mn1 = fminf(mn1, p1); mx1 = fmaxf(mx1, p1);
                }
            }
            bx1 = mn0; by1 = mn1; bx2 = mx0; by2 = mx1;
#pragma unroll
            for (int mm = 0; mm < 16; ++mm) sm->data16[k][mm] = c16[mm];
        } else {
            float4 r = *(const float4*)(raw + ((size_t)img * N + si) * 4);
            float cx = r.x, cy = r.y, w = r.z, h = r.w;
            bx1 = (cx - 0.5f * w) * Wimg;
            by1 = (cy - 0.5f * h) * Himg;
            bx2 = (cx + 0.5f * w) * Wimg;
            by2 = (cy + 0.5f * h) * Himg;
            if (!HAS_PARENT) {  // block level: clip to [0, (W,H)]
                bx1 = fminf(fmaxf(bx1, 0.0f), Wimg);
                by1 = fminf(fmaxf(by1, 0.0f), Himg);
                bx2 = fminf(fmaxf(bx2, 0.0f), Wimg);
                by2 = fminf(fmaxf(by2, 0.0f), Himg);
            }
        }
        sm->box[k][0] = bx1; sm->box[k][1] = by1;
        sm->box[k][2] = bx2; sm->box[k][3] = by2;
        sm->area[k] = (bx2 - bx1) * (by2 - by1);
        sm->keep[k] = keep ? 1 : 0;

        if (HAS_PARENT) {
            int pi = si / ef;
            float4 pr = *(const float4*)(parent_raw + ((size_t)img * PN + pi) * 4);
            float px1 = (pr.x - 0.5f * pr.z) * Wimg;
            float py1 = (pr.y - 0.5f * pr.w) * Himg;
            float px2 = (pr.x + 0.5f * pr.z) * Wimg;
            float py2 = (pr.y + 0.5f * pr.w) * Himg;
            float ix1 = fmaxf(bx1, px1), iy1 = fmaxf(by1, py1);
            float ix2 = fminf(bx2, px2), iy2 = fminf(by2, py2);
            float inter = fmaxf(ix2 - ix1, 0.0f) * fmaxf(iy2 - iy1, 0.0f);
            float carea = (bx2 - bx1) * (by2 - by1);
            float belong = inter / (carea + 1e-6f);
            sm->belong[k] = belong;
            sm->valid[k] = (belong > BELONG_TH) ? 1 : 0;
        }
    }
    __syncthreads();

    // ---- parent validity combine (wave 0) ----
    if (HAS_PARENT) {
        if (tid < 64) {
            ull k0 = make_key(sm->keep[tid] ? sm->belong[tid] : -INFINITY, (unsigned)tid);
            bool p0 = sm->valid[tid] && sm->keep[tid];
            ull k1 = 0;
            bool p1 = false;
            if (tid < KSEL - 64) {
                k1 = make_key(sm->keep[tid + 64] ? sm->belong[tid + 64] : -INFINITY,
                              (unsigned)(tid + 64));
                p1 = sm->valid[tid + 64] && sm->keep[tid + 64];
            }
            ull m = k0 > k1 ? k0 : k1;
#pragma unroll
            for (int off = 32; off > 0; off >>= 1) {
                ull o = __shfl_xor(m, off, 64);
                if (o > m) m = o;
            }
            ull bal = __ballot(p0 || p1);
            if (lane == 0) {
                sm->argm = (int)key_idx(m);   // first max (smallest k on ties)
                sm->anyvk = (bal != 0ULL) ? 1 : 0;
            }
        }
        __syncthreads();
        if (tid < KSEL) {
            bool valid = sm->anyvk ? (sm->valid[tid] != 0) : (tid == sm->argm);
            sm->nk[tid] = (sm->keep[tid] && valid) ? 1 : 0;
        }
    } else {
        if (tid < KSEL) sm->nk[tid] = sm->keep[tid];
    }
    __syncthreads();

    // ---- NMS phase 1: build 100x128 suppression bit-matrix in parallel.
    //      row i bit j = (iou(i,j) > TH) && (j > i). All 16 waves participate. ----
    {
        float4 b0 = *(const float4*)sm->box[lane];
        float a0 = sm->area[lane];
        float4 b1 = make_float4(0.f, 0.f, 0.f, 0.f);
        float a1 = 0.f;
        if (lane < KSEL - 64) {
            b1 = *(const float4*)sm->box[lane + 64];
            a1 = sm->area[lane + 64];
        }
        for (int i = wv; i < KSEL; i += NWAVES) {
            float rx1, ry1, rx2, ry2, ra;
            if (i < 64) {
                rx1 = __shfl(b0.x, i, 64); ry1 = __shfl(b0.y, i, 64);
                rx2 = __shfl(b0.z, i, 64); ry2 = __shfl(b0.w, i, 64);
                ra  = __shfl(a0, i, 64);
            } else {
                rx1 = __shfl(b1.x, i - 64, 64); ry1 = __shfl(b1.y, i - 64, 64);
                rx2 = __shfl(b1.z, i - 64, 64); ry2 = __shfl(b1.w, i - 64, 64);
                ra  = __shfl(a1, i - 64, 64);
            }
            // slot 0: j = lane
            float ix1 = fmaxf(rx1, b0.x), iy1 = fmaxf(ry1, b0.y);
            float ix2 = fminf(rx2, b0.z), iy2 = fminf(ry2, b0.w);
            float in0 = fmaxf(ix2 - ix1, 0.0f) * fmaxf(iy2 - iy1, 0.0f);
            float iou0 = in0 / (ra + a0 - in0);
            bool sup0 = (lane > i) && (iou0 > NMS_TH);  // NaN>th == false
            // slot 1: j = lane + 64
            float jx1 = fmaxf(rx1, b1.x), jy1 = fmaxf(ry1, b1.y);
            float jx2 = fminf(rx2, b1.z), jy2 = fminf(ry2, b1.w);
            float in1 = fmaxf(jx2 - jx1, 0.0f) * fmaxf(jy2 - jy1, 0.0f);
            float iou1 = in1 / (ra + a1 - in1);
            bool sup1 = (lane < KSEL - 64) && ((lane + 64) > i) && (iou1 > NMS_TH);
            ull w0 = __ballot(sup0);
            ull w1 = __ballot(sup1);
            if (lane == 0) { sm->nmsrow[i][0] = w0; sm->nmsrow[i][1] = w1; }
        }
    }
    __syncthreads();

    // ---- NMS phase 2: sequential sweep, skipping suppressed rows via ctz.
    //      Iterations == #survivors (uniform control flow; masks replicated). ----
    if (tid < 64) {
        const int l = lane;
        ull r0lo = sm->nmsrow[l][0], r0hi = sm->nmsrow[l][1];
        ull r1hi = 0;
        if (l < KSEL - 64) r1hi = sm->nmsrow[l + 64][1];
        ull keepLo = __ballot(sm->nk[l] != 0);
        ull keepHi = __ballot((l < KSEL - 64) && (sm->nk[l + 64] != 0));
        ull remLo = keepLo, remHi = keepHi;
        while (remLo | remHi) {
            if (remLo) {
                int i = __builtin_ctzll(remLo);
                ull slo = __shfl(r0lo, i, 64);
                ull shi = __shfl(r0hi, i, 64);
                keepLo &= ~slo;
                keepHi &= ~shi;
                ull gt = (i >= 63) ? 0ULL : (~0ULL << (i + 1));
                remLo = keepLo & gt;
                remHi = keepHi;
            } else {
                int i = __builtin_ctzll(remHi);  // row i+64 suppresses only hi bits
                ull shi = __shfl(r1hi, i, 64);
                keepHi &= ~shi;
                ull gt = (i >= 63) ? 0ULL : (~0ULL << (i + 1));
                remHi = keepHi & gt;
                remLo = 0;
            }
        }
        sm->nk[l] = (unsigned char)((keepLo >> l) & 1ULL);
        if (l < KSEL - 64) sm->nk[l + 64] = (unsigned char)((keepHi >> l) & 1ULL);
    }
    __syncthreads();

    // ---- outputs ----
    if (tid < KSEL) {
        const int k = tid;
        const bool nk = sm->nk[k] != 0;
        out_scores[(size_t)img * KSEL + k] = nk ? sm->prob[k] : 0.0f;
        out_keep[(size_t)img * KSEL + k] = nk ? 1.0f : 0.0f;
        if (IS_BEZIER) {
#pragma unroll
            for (int mm = 0; mm < 16; ++mm)
                out_data[((size_t)img * KSEL + k) * 16 + mm] = nk ? sm->data16[k][mm] : 0.0f;
        } else {
#pragma unroll
            for (int mm = 0; mm < 4; ++mm)
                out_data[((size_t)img * KSEL + k) * 4 + mm] = nk ? sm->box[k][mm] : 0.0f;
        }
    }
}

__global__ __launch_bounds__(NTHREADS) void postprocess_kernel(
    const float* __restrict__ blk_logits, const float* __restrict__ lin_logits,
    const float* __restrict__ chr_logits, const float* __restrict__ blk_raw,
    const float* __restrict__ lin_raw, const float* __restrict__ chr_raw,
    const float* __restrict__ tsizes, float* __restrict__ out) {
    __shared__ SharedMem sm;
    const int b = blockIdx.x;
    const int level = b >> 6;  // 64 images per level
    const int img = b & 63;

    // output layout (B=64, K=100): blk(data,sc,kp), lin(data,sc,kp), chr(data16,sc,kp)
    float* blk_data = out + 0;
    float* blk_sc   = out + 25600;
    float* blk_kp   = out + 32000;
    float* lin_data = out + 38400;
    float* lin_sc   = out + 64000;
    float* lin_kp   = out + 70400;
    float* chr_data = out + 76800;
    float* chr_sc   = out + 179200;
    float* chr_kp   = out + 185600;

    if (level == 0) {
        filter_impl<4, false, false>(&sm, blk_logits, blk_raw, nullptr, tsizes,
                                     blk_data, blk_sc, blk_kp, img, 4096, 0, 1);
    } else if (level == 1) {
        filter_impl<16, false, true>(&sm, lin_logits, lin_raw, blk_raw, tsizes,
                                     lin_data, lin_sc, lin_kp, img, 16384, 4096, 4);
    } else {
        filter_impl<16, true, true>(&sm, chr_logits, chr_raw, lin_raw, tsizes,
                                    chr_data, chr_sc, chr_kp, img, 16384, 16384, 1);
    }
}

extern "C" void kernel_launch(void* const* d_in, const int* in_sizes, int n_in,
                              void* d_out, int out_size, void* d_ws, size_t ws_size,
                              hipStream_t stream) {
    (void)in_sizes; (void)n_in; (void)d_ws; (void)ws_size; (void)out_size;
    const float* blk_logits = (const float*)d_in[0];
    const float* lin_logits = (const float*)d_in[1];
    const float* chr_logits = (const float*)d_in[2];
    const float* blk_raw = (const float*)d_in[3];
    const float* lin_raw = (const float*)d_in[4];
    const float* chr_raw = (const float*)d_in[5];
    const float* tsz = (const float*)d_in[6];
    float* out = (float*)d_out;

    hipLaunchKernelGGL(postprocess_kernel, dim3(192), dim3(NTHREADS), 0, stream,
                       blk_logits, lin_logits, chr_logits, blk_raw, lin_raw,
                       chr_raw, tsz, out);
}